// Round 4
// baseline (231.212 us; speedup 1.0000x reference)
//
#include <hip/hip_runtime.h>
#include <cstdint>
#include <cstring>
#include <algorithm>

#define NCELLS (48*48*48)   // 110592
#define NT 48
#define CB 64               // cells per block in k_cell
#define NW 4                // waves per block; each wave does NT/NW = 12 tris
#define TPW 12              // tris per wave
#define PITCH 97            // LDS row pitch (97 % 32 == 1 -> 2-way conflict = free)

// Linearized per-tri tables. u = ub + d1*A1 - d0*A0 ; w = wb + d2*A2 - d0*A0
// (A* are one-hot axis vectors; ub/wb are const base-vertex differences).
// 3648 bytes -> fits kernarg. All accesses use compile-time t so they fold
// to scalar loads (R3's runtime-indexed accesses were per-lane global_loads).
struct TriTab2 {
  int   delta[NT][3];   // element delta into offset array per (tri, vertex)
  float ub[NT][3];      // B1 - B0
  float wb[NT][3];      // B2 - B0
  float A0[NT][3];      // one-hot axis of vertex 0
  float A1[NT][3];
  float A2[NT][3];
  int   tto[NT];        // TT_IDX[t]
};

// ---------------- host-side exact numpy RNG reproduction ----------------
namespace nprng {
typedef unsigned __int128 u128;
struct PCG { u128 state, inc; int has32; uint32_t cached; };

static inline u128 mult128() {
  return (((u128)2549297995355413924ULL) << 64) | (u128)4865540595714422341ULL;
}
static inline void step(PCG& g) { g.state = g.state * mult128() + g.inc; }
static inline uint64_t out64(const PCG& g) {
  uint64_t x = (uint64_t)(g.state >> 64) ^ (uint64_t)g.state;
  unsigned rot = (unsigned)(g.state >> 122);
  return (x >> rot) | (x << ((64u - rot) & 63u));
}
static inline uint64_t next64(PCG& g) { step(g); return out64(g); }
static inline uint32_t next32(PCG& g) {
  if (g.has32) { g.has32 = 0; return g.cached; }
  uint64_t v = next64(g);
  g.has32 = 1; g.cached = (uint32_t)(v >> 32);
  return (uint32_t)v;
}
static inline uint32_t lemire32(PCG& g, uint32_t rngmax) {
  const uint32_t rng_excl = rngmax + 1u;
  uint64_t m = (uint64_t)next32(g) * (uint64_t)rng_excl;
  uint32_t leftover = (uint32_t)m;
  if (leftover < rng_excl) {
    const uint32_t threshold = (uint32_t)((0xFFFFFFFFu - rngmax) % rng_excl);
    while (leftover < threshold) {
      m = (uint64_t)next32(g) * (uint64_t)rng_excl;
      leftover = (uint32_t)m;
    }
  }
  return (uint32_t)(m >> 32);
}
static inline uint64_t rbu(PCG& g, uint64_t rngmax) {
  if (rngmax == 0) return 0;
  return (uint64_t)lemire32(g, (uint32_t)rngmax);
}
static void seed_pcg0(PCG& g) {
  const uint32_t INIT_A = 0x43b0d7e5u, MULT_A = 0x931e8875u;
  const uint32_t INIT_B = 0x8b51f9ddu, MULT_B = 0x58f38dedu;
  const uint32_t MIX_L = 0xca01f9ddu, MIX_R = 0x4973f715u;
  uint32_t pool[4];
  uint32_t hc = INIT_A;
  auto hashmix = [&](uint32_t v) { v ^= hc; hc *= MULT_A; v *= hc; v ^= v >> 16; return v; };
  auto mix = [&](uint32_t x, uint32_t y) { uint32_t r = MIX_L * x - MIX_R * y; r ^= r >> 16; return r; };
  for (int i = 0; i < 4; i++) pool[i] = hashmix(0u);
  for (int s = 0; s < 4; s++)
    for (int d = 0; d < 4; d++)
      if (s != d) pool[d] = mix(pool[d], hashmix(pool[s]));
  uint32_t st[8];
  uint32_t hb = INIT_B;
  for (int i = 0; i < 8; i++) {
    uint32_t v = pool[i & 3];
    v ^= hb; hb *= MULT_B; v *= hb; v ^= v >> 16;
    st[i] = v;
  }
  uint64_t w[4];
  for (int i = 0; i < 4; i++) w[i] = (uint64_t)st[2 * i] | ((uint64_t)st[2 * i + 1] << 32);
  u128 initstate = (((u128)w[0]) << 64) | (u128)w[1];
  u128 initseq   = (((u128)w[2]) << 64) | (u128)w[3];
  g.state = 0; g.inc = (initseq << 1) | (u128)1;
  step(g); g.state += initstate; step(g);
  g.has32 = 0; g.cached = 0;
}
static void choice_nr(PCG& g, int pop, int n, int* outv, bool shuf) {
  uint64_t hs[64];
  uint64_t set_size = (uint64_t)(1.2 * (double)n);
  uint64_t mask = set_size;
  mask |= mask >> 1; mask |= mask >> 2; mask |= mask >> 4;
  mask |= mask >> 8; mask |= mask >> 16; mask |= mask >> 32;
  uint64_t ss = mask + 1;
  for (uint64_t i = 0; i < ss; i++) hs[i] = ~0ULL;
  for (int j = pop - n; j < pop; j++) {
    uint64_t val = rbu(g, (uint64_t)j);
    uint64_t loc = val & mask;
    while (hs[loc] != ~0ULL && hs[loc] != val) loc = (loc + 1) & mask;
    if (hs[loc] == ~0ULL) { hs[loc] = val; outv[j - (pop - n)] = (int)val; }
    else {
      loc = (uint64_t)j & mask;
      while (hs[loc] != ~0ULL) loc = (loc + 1) & mask;
      hs[loc] = (uint64_t)j;
      outv[j - (pop - n)] = j;
    }
  }
  if (shuf) {
    for (int i = n - 1; i >= 1; i--) {
      uint64_t j = rbu(g, (uint64_t)i);
      int t = outv[i]; outv[i] = outv[(int)j]; outv[(int)j] = t;
    }
  }
}
} // namespace nprng

static void build_tab(TriTab2* T) {
  nprng::PCG g;
  nprng::seed_pcg0(g);
  int tri[NT][3];
  for (int t = 0; t < NT; t++) nprng::choice_nr(g, 12, 3, tri[t], true);
  int tt[NT];
  nprng::choice_nr(g, 96, NT, tt, true);
  std::sort(tt, tt + NT);
  static const int EC[12][3] = {{0,0,0},{0,1,0},{0,0,1},{0,1,1},
                                {0,0,0},{1,0,0},{0,0,1},{1,0,1},
                                {0,0,0},{1,0,0},{0,1,0},{1,1,0}};
  static const int EA[12] = {0,0,0,0,1,1,1,1,2,2,2,2};
  for (int t = 0; t < NT; t++) {
    float B[3][3];
    int ax[3];
    for (int k = 0; k < 3; k++) {
      int e = tri[t][k];
      int a = EA[e];
      ax[k] = a;
      T->delta[t][k] = a * 117649 + EC[e][0] * 2401 + EC[e][1] * 49 + EC[e][2];
      B[k][0] = (float)EC[e][0]; B[k][1] = (float)EC[e][1]; B[k][2] = (float)EC[e][2];
      B[k][a] += 0.5f;
    }
    for (int c = 0; c < 3; c++) {
      T->ub[t][c] = B[1][c] - B[0][c];
      T->wb[t][c] = B[2][c] - B[0][c];
      T->A0[t][c] = (ax[0] == c) ? 1.0f : 0.0f;
      T->A1[t][c] = (ax[1] == c) ? 1.0f : 0.0f;
      T->A2[t][c] = (ax[2] == c) ? 1.0f : 0.0f;
    }
    T->tto[t] = tt[t];
  }
}

// ---------------- kernels ----------------
// 12-tri body with COMPILE-TIME tri indices (T0+k after full unroll) so all
// TriTab2 kernarg accesses fold to scalar loads instead of per-lane vmem.
template <int T0>
__device__ __forceinline__ void do12(const TriTab2& tab, const float* __restrict__ off,
                                     int base, const float* __restrict__ myrow,
                                     float& s, float& mx, float& my, float& mz) {
#pragma unroll
  for (int k = 0; k < TPW; k++) {
    const int t = T0 + k;  // compile-time after unroll
    float p  = myrow[tab.tto[t]];
    float d0 = off[base + tab.delta[t][0]];
    float d1 = off[base + tab.delta[t][1]];
    float d2 = off[base + tab.delta[t][2]];
    float ux = tab.ub[t][0] + d1 * tab.A1[t][0] - d0 * tab.A0[t][0];
    float uy = tab.ub[t][1] + d1 * tab.A1[t][1] - d0 * tab.A0[t][1];
    float uz = tab.ub[t][2] + d1 * tab.A1[t][2] - d0 * tab.A0[t][2];
    float wx = tab.wb[t][0] + d2 * tab.A2[t][0] - d0 * tab.A0[t][0];
    float wy = tab.wb[t][1] + d2 * tab.A2[t][1] - d0 * tab.A0[t][1];
    float wz = tab.wb[t][2] + d2 * tab.A2[t][2] - d0 * tab.A0[t][2];
    float cxv = uy * wz - uz * wy;
    float cyv = uz * wx - ux * wz;
    float czv = ux * wy - uy * wx;
    float nn = cxv * cxv + cyv * cyv + czv * czv + 1e-8f;
    float rinv = rsqrtf(nn);
    s += p;
    float f = p * rinv;
    mx += f * cxv;
    my += f * cyv;
    mz += f * czv;
  }
}

// k_cell: 64 cells/block, 256 threads (4 waves). Wave w computes tris
// [12w, 12w+12) for lane's cell; partials reduced across waves via LDS.
__global__ __launch_bounds__(CB * NW) void k_cell(const float* __restrict__ off,
                                                  const float* __restrict__ topo,
                                                  float4* __restrict__ ws4,
                                                  float* __restrict__ out,
                                                  TriTab2 tab) {
  __shared__ float lds[CB * PITCH];
  __shared__ float4 red[CB * NW];
  const int tid = threadIdx.x;
  const int lane = tid & 63;     // local cell
  const int wv = tid >> 6;       // tri-quarter
  const int cell0 = blockIdx.x * CB;

  if (blockIdx.x == 0 && tid == 0) *out = 0.0f;  // zero accumulator for k_pair

  // ---- coalesced staging: 64 rows x 24 float4 = 1536 float4, linear ----
  const float4* trow = (const float4*)(topo + (size_t)cell0 * 96);
#pragma unroll
  for (int it = 0; it < 6; ++it) {
    int ch = tid + CB * NW * it;
    float4 v = trow[ch];
    int r  = ch / 24;
    int c4 = (ch % 24) * 4;
    float* dst = &lds[r * PITCH + c4];
    dst[0] = v.x; dst[1] = v.y; dst[2] = v.z; dst[3] = v.w;
  }
  __syncthreads();

  // ---- per-(cell, quarter) compute ----
  const int cell = cell0 + lane;
  const int z = cell % 48;
  const int y = (cell / 48) % 48;
  const int x = cell / 2304;
  const int base = (x * 49 + y) * 49 + z;
  const float* myrow = &lds[lane * PITCH];

  float s = 0.f, mx = 0.f, my = 0.f, mz = 0.f;
  switch (wv) {   // wave-uniform branch -> no divergence; t compile-time inside
    case 0: do12<0>(tab, off, base, myrow, s, mx, my, mz); break;
    case 1: do12<12>(tab, off, base, myrow, s, mx, my, mz); break;
    case 2: do12<24>(tab, off, base, myrow, s, mx, my, mz); break;
    default: do12<36>(tab, off, base, myrow, s, mx, my, mz); break;
  }
  red[tid] = make_float4(s, mx, my, mz);
  __syncthreads();

  // ---- cross-wave combine: wave 0 sums the 4 quarters, writes float4 ----
  if (wv == 0) {
    float4 a = red[lane];
    float4 b = red[lane + 64];
    float4 c = red[lane + 128];
    float4 d = red[lane + 192];
    ws4[cell0 + lane] = make_float4(a.x + b.x + c.x + d.x,
                                    a.y + b.y + c.y + d.y,
                                    a.z + b.z + c.z + d.z,
                                    a.w + b.w + c.w + d.w);
  }
}

__global__ __launch_bounds__(256) void k_pair(const float4* __restrict__ ws4,
                                              float* __restrict__ out) {
  int cell = blockIdx.x * 256 + threadIdx.x;
  int z = cell % 48;
  int y = (cell / 48) % 48;
  int x = cell / 2304;
  float4 a = ws4[cell];
  float acc = a.x * a.x - (a.y * a.y + a.z * a.z + a.w * a.w);
  if (z < 47) {
    float4 b = ws4[cell + 1];
    acc += a.x * b.x - (a.y * b.y + a.z * b.z + a.w * b.w);
  }
  if (y < 47) {
    float4 b = ws4[cell + 48];
    acc += a.x * b.x - (a.y * b.y + a.z * b.z + a.w * b.w);
  }
  if (x < 47) {
    float4 b = ws4[cell + 2304];
    acc += a.x * b.x - (a.y * b.y + a.z * b.z + a.w * b.w);
  }
  acc *= 2.0f;
  for (int o = 32; o > 0; o >>= 1) acc += __shfl_down(acc, o, 64);
  __shared__ float lds[4];
  int lane = threadIdx.x & 63;
  int w = threadIdx.x >> 6;
  if (lane == 0) lds[w] = acc;
  __syncthreads();
  if (threadIdx.x == 0) atomicAdd(out, lds[0] + lds[1] + lds[2] + lds[3]);
}

extern "C" void kernel_launch(void* const* d_in, const int* in_sizes, int n_in,
                              void* d_out, int out_size, void* d_ws, size_t ws_size,
                              hipStream_t stream) {
  const float* off  = (const float*)d_in[0];   // [3,49,49,49] f32
  const float* topo = (const float*)d_in[1];   // [110592,96] f32
  float4* ws4 = (float4*)d_ws;                 // 110592 float4 = 1.77 MB
  float* out  = (float*)d_out;                 // scalar f32

  TriTab2 T;
  build_tab(&T);

  k_cell<<<dim3(NCELLS / CB), dim3(CB * NW), 0, stream>>>(off, topo, ws4, out, T);
  k_pair<<<dim3(NCELLS / 256), dim3(256), 0, stream>>>(ws4, out);
}

// Round 5
// 91.288 us; speedup vs baseline: 2.5328x; 2.5328x over previous
//
#include <hip/hip_runtime.h>
#include <cstdint>

#define NCELLS (48*48*48)   // 110592
#define NT 48
#define CB 64               // cells per block in k_cell
#define NW 4                // waves per block; each wave does 12 tris
#define PITCH 97            // LDS row pitch (97 % 32 == 1 -> 2 lanes/bank = free)

// ---------------- compile-time exact numpy RNG reproduction ----------------
// Tables are deterministic (np.random.default_rng(0) at module import), so the
// whole RNG pipeline runs in constexpr and TAB folds to immediates in codegen.
namespace nprng {
typedef unsigned __int128 u128;
struct PCG { u128 state; u128 inc; int has32; uint32_t cached; };

constexpr u128 mult128() {
  return (((u128)2549297995355413924ULL) << 64) | (u128)4865540595714422341ULL;
}
constexpr void step(PCG& g) { g.state = g.state * mult128() + g.inc; }
constexpr uint64_t out64(const PCG& g) {
  uint64_t x = (uint64_t)(g.state >> 64) ^ (uint64_t)g.state;
  unsigned rot = (unsigned)(g.state >> 122);
  return (x >> rot) | (x << ((64u - rot) & 63u));
}
constexpr uint64_t next64(PCG& g) { step(g); return out64(g); }
constexpr uint32_t next32(PCG& g) {
  if (g.has32) { g.has32 = 0; return g.cached; }
  uint64_t v = next64(g);
  g.has32 = 1; g.cached = (uint32_t)(v >> 32);
  return (uint32_t)v;
}
constexpr uint32_t lemire32(PCG& g, uint32_t rngmax) {
  const uint32_t rng_excl = rngmax + 1u;
  uint64_t m = (uint64_t)next32(g) * (uint64_t)rng_excl;
  uint32_t leftover = (uint32_t)m;
  if (leftover < rng_excl) {
    const uint32_t threshold = (uint32_t)((0xFFFFFFFFu - rngmax) % rng_excl);
    while (leftover < threshold) {
      m = (uint64_t)next32(g) * (uint64_t)rng_excl;
      leftover = (uint32_t)m;
    }
  }
  return (uint32_t)(m >> 32);
}
constexpr uint64_t rbu(PCG& g, uint64_t rngmax) {
  if (rngmax == 0) return 0;
  return (uint64_t)lemire32(g, (uint32_t)rngmax);
}
constexpr uint32_t hashmix(uint32_t v, uint32_t& hc) {
  v ^= hc; hc *= 0x931e8875u; v *= hc; v ^= v >> 16; return v;
}
constexpr uint32_t mix2(uint32_t x, uint32_t y) {
  uint32_t r = 0xca01f9ddu * x - 0x4973f715u * y; r ^= r >> 16; return r;
}
constexpr PCG seed_pcg0() {
  PCG g{0, 0, 0, 0};
  uint32_t pool[4] = {};
  uint32_t hc = 0x43b0d7e5u;
  for (int i = 0; i < 4; i++) pool[i] = hashmix(0u, hc);
  for (int s = 0; s < 4; s++)
    for (int d = 0; d < 4; d++)
      if (s != d) pool[d] = mix2(pool[d], hashmix(pool[s], hc));
  uint32_t st[8] = {};
  uint32_t hb = 0x8b51f9ddu;
  for (int i = 0; i < 8; i++) {
    uint32_t v = pool[i & 3];
    v ^= hb; hb *= 0x58f38dedu; v *= hb; v ^= v >> 16;
    st[i] = v;
  }
  uint64_t w[4] = {};
  for (int i = 0; i < 4; i++) w[i] = (uint64_t)st[2 * i] | ((uint64_t)st[2 * i + 1] << 32);
  u128 initstate = (((u128)w[0]) << 64) | (u128)w[1];
  u128 initseq   = (((u128)w[2]) << 64) | (u128)w[3];
  g.state = 0; g.inc = (initseq << 1) | (u128)1;
  step(g); g.state += initstate; step(g);
  g.has32 = 0; g.cached = 0;
  return g;
}
constexpr void choice_nr(PCG& g, int pop, int n, int* outv, bool shuf) {
  uint64_t hs[64] = {};
  uint64_t set_size = (uint64_t)(1.2 * (double)n);
  uint64_t mask = set_size;
  mask |= mask >> 1; mask |= mask >> 2; mask |= mask >> 4;
  mask |= mask >> 8; mask |= mask >> 16; mask |= mask >> 32;
  for (int i = 0; i < 64; i++) hs[i] = ~0ULL;
  for (int j = pop - n; j < pop; j++) {
    uint64_t val = rbu(g, (uint64_t)j);
    uint64_t loc = val & mask;
    while (hs[loc] != ~0ULL && hs[loc] != val) loc = (loc + 1) & mask;
    if (hs[loc] == ~0ULL) { hs[loc] = val; outv[j - (pop - n)] = (int)val; }
    else {
      loc = (uint64_t)j & mask;
      while (hs[loc] != ~0ULL) loc = (loc + 1) & mask;
      hs[loc] = (uint64_t)j;
      outv[j - (pop - n)] = j;
    }
  }
  if (shuf) {
    for (int i = n - 1; i >= 1; i--) {
      uint64_t j = rbu(g, (uint64_t)i);
      int t = outv[i]; outv[i] = outv[(int)j]; outv[(int)j] = t;
    }
  }
}
} // namespace nprng

struct TriTab3 {
  int   delta[NT][3];   // element delta into offset array per (tri, vertex)
  float ub[NT][3];      // B1 - B0
  float wb[NT][3];      // B2 - B0
  int   a0[NT], a1[NT], a2[NT];  // displacement axes
  int   tto[NT];        // TT_IDX[t]
};

constexpr TriTab3 make_tab() {
  TriTab3 T{};
  nprng::PCG g = nprng::seed_pcg0();
  int tri[NT][3] = {};
  for (int t = 0; t < NT; t++) nprng::choice_nr(g, 12, 3, tri[t], true);
  int tt[NT] = {};
  nprng::choice_nr(g, 96, NT, tt, true);
  // insertion sort (std::sort is not constexpr in C++17)
  for (int i = 1; i < NT; i++) {
    int v = tt[i], j = i - 1;
    while (j >= 0 && tt[j] > v) { tt[j + 1] = tt[j]; j--; }
    tt[j + 1] = v;
  }
  constexpr int EC[12][3] = {{0,0,0},{0,1,0},{0,0,1},{0,1,1},
                             {0,0,0},{1,0,0},{0,0,1},{1,0,1},
                             {0,0,0},{1,0,0},{0,1,0},{1,1,0}};
  constexpr int EA[12] = {0,0,0,0,1,1,1,1,2,2,2,2};
  for (int t = 0; t < NT; t++) {
    float B[3][3] = {};
    int ax[3] = {};
    for (int k = 0; k < 3; k++) {
      int e = tri[t][k];
      int a = EA[e];
      ax[k] = a;
      T.delta[t][k] = a * 117649 + EC[e][0] * 2401 + EC[e][1] * 49 + EC[e][2];
      B[k][0] = (float)EC[e][0]; B[k][1] = (float)EC[e][1]; B[k][2] = (float)EC[e][2];
      B[k][a] += 0.5f;
    }
    for (int c = 0; c < 3; c++) {
      T.ub[t][c] = B[1][c] - B[0][c];
      T.wb[t][c] = B[2][c] - B[0][c];
    }
    T.a0[t] = ax[0]; T.a1[t] = ax[1]; T.a2[t] = ax[2];
    T.tto[t] = tt[t];
  }
  return T;
}

static constexpr TriTab3 TAB = make_tab();

// ---------------- kernels ----------------
// One triangle, ALL table values compile-time immediates (zero table loads;
// one-hot axis selects fold; off[] loads CSE across triangles sharing edges).
template <int t>
__device__ __forceinline__ void do1(const float* __restrict__ off, int base,
                                    const float* __restrict__ myrow,
                                    float& s, float& mx, float& my, float& mz) {
  constexpr int D0 = TAB.delta[t][0], D1 = TAB.delta[t][1], D2 = TAB.delta[t][2];
  constexpr int A0 = TAB.a0[t], A1 = TAB.a1[t], A2 = TAB.a2[t];
  float p  = myrow[TAB.tto[t]];
  float d0 = off[base + D0];
  float d1 = off[base + D1];
  float d2 = off[base + D2];
  float ux = TAB.ub[t][0] + (A1 == 0 ? d1 : 0.0f) - (A0 == 0 ? d0 : 0.0f);
  float uy = TAB.ub[t][1] + (A1 == 1 ? d1 : 0.0f) - (A0 == 1 ? d0 : 0.0f);
  float uz = TAB.ub[t][2] + (A1 == 2 ? d1 : 0.0f) - (A0 == 2 ? d0 : 0.0f);
  float wx = TAB.wb[t][0] + (A2 == 0 ? d2 : 0.0f) - (A0 == 0 ? d0 : 0.0f);
  float wy = TAB.wb[t][1] + (A2 == 1 ? d2 : 0.0f) - (A0 == 1 ? d0 : 0.0f);
  float wz = TAB.wb[t][2] + (A2 == 2 ? d2 : 0.0f) - (A0 == 2 ? d0 : 0.0f);
  float cxv = uy * wz - uz * wy;
  float cyv = uz * wx - ux * wz;
  float czv = ux * wy - uy * wx;
  float nn = cxv * cxv + cyv * cyv + czv * czv + 1e-8f;
  float rinv = rsqrtf(nn);
  s += p;
  float f = p * rinv;
  mx += f * cxv;
  my += f * cyv;
  mz += f * czv;
}

template <int T0>
__device__ __forceinline__ void do12(const float* __restrict__ off, int base,
                                     const float* __restrict__ myrow,
                                     float& s, float& mx, float& my, float& mz) {
  do1<T0 + 0>(off, base, myrow, s, mx, my, mz);
  do1<T0 + 1>(off, base, myrow, s, mx, my, mz);
  do1<T0 + 2>(off, base, myrow, s, mx, my, mz);
  do1<T0 + 3>(off, base, myrow, s, mx, my, mz);
  do1<T0 + 4>(off, base, myrow, s, mx, my, mz);
  do1<T0 + 5>(off, base, myrow, s, mx, my, mz);
  do1<T0 + 6>(off, base, myrow, s, mx, my, mz);
  do1<T0 + 7>(off, base, myrow, s, mx, my, mz);
  do1<T0 + 8>(off, base, myrow, s, mx, my, mz);
  do1<T0 + 9>(off, base, myrow, s, mx, my, mz);
  do1<T0 + 10>(off, base, myrow, s, mx, my, mz);
  do1<T0 + 11>(off, base, myrow, s, mx, my, mz);
}

// 64 cells/block, 256 threads (4 waves); wave w -> tris [12w, 12w+12).
// readfirstlane makes the wave id provably SGPR-uniform -> scalar branches,
// each wave executes exactly ONE folded-constant body (R4's exec-mask
// fall-through ran all four).
__global__ __launch_bounds__(CB * NW) void k_cell(const float* __restrict__ off,
                                                  const float* __restrict__ topo,
                                                  float4* __restrict__ ws4,
                                                  float* __restrict__ out) {
  __shared__ float lds[CB * PITCH];
  __shared__ float4 red[CB * NW];
  const int tid = threadIdx.x;
  const int lane = tid & 63;
  const int cell0 = blockIdx.x * CB;

  if (blockIdx.x == 0 && tid == 0) *out = 0.0f;  // zero accumulator for k_pair

  // ---- coalesced staging: 64 rows x 24 float4 = 1536 float4, linear ----
  const float4* trow = (const float4*)(topo + (size_t)cell0 * 96);
#pragma unroll
  for (int it = 0; it < 6; ++it) {
    int ch = tid + CB * NW * it;
    float4 v = trow[ch];
    int r  = ch / 24;
    int c4 = (ch % 24) * 4;
    float* dst = &lds[r * PITCH + c4];
    dst[0] = v.x; dst[1] = v.y; dst[2] = v.z; dst[3] = v.w;
  }
  __syncthreads();

  // ---- per-(cell, quarter) compute ----
  const int cell = cell0 + lane;
  const int z = cell % 48;
  const int y = (cell / 48) % 48;
  const int x = cell / 2304;
  const int base = (x * 49 + y) * 49 + z;
  const float* myrow = &lds[lane * PITCH];

  float s = 0.f, mx = 0.f, my = 0.f, mz = 0.f;
  const int wvu = __builtin_amdgcn_readfirstlane(tid >> 6);  // SGPR-uniform
  if (wvu == 0)      do12<0>(off, base, myrow, s, mx, my, mz);
  else if (wvu == 1) do12<12>(off, base, myrow, s, mx, my, mz);
  else if (wvu == 2) do12<24>(off, base, myrow, s, mx, my, mz);
  else               do12<36>(off, base, myrow, s, mx, my, mz);

  red[tid] = make_float4(s, mx, my, mz);
  __syncthreads();

  // ---- cross-wave combine: wave 0 sums the 4 quarters, writes float4 ----
  if (tid < 64) {
    float4 a = red[lane];
    float4 b = red[lane + 64];
    float4 c = red[lane + 128];
    float4 d = red[lane + 192];
    ws4[cell0 + lane] = make_float4(a.x + b.x + c.x + d.x,
                                    a.y + b.y + c.y + d.y,
                                    a.z + b.z + c.z + d.z,
                                    a.w + b.w + c.w + d.w);
  }
}

__global__ __launch_bounds__(256) void k_pair(const float4* __restrict__ ws4,
                                              float* __restrict__ out) {
  int cell = blockIdx.x * 256 + threadIdx.x;
  int z = cell % 48;
  int y = (cell / 48) % 48;
  int x = cell / 2304;
  float4 a = ws4[cell];
  float acc = a.x * a.x - (a.y * a.y + a.z * a.z + a.w * a.w);
  if (z < 47) {
    float4 b = ws4[cell + 1];
    acc += a.x * b.x - (a.y * b.y + a.z * b.z + a.w * b.w);
  }
  if (y < 47) {
    float4 b = ws4[cell + 48];
    acc += a.x * b.x - (a.y * b.y + a.z * b.z + a.w * b.w);
  }
  if (x < 47) {
    float4 b = ws4[cell + 2304];
    acc += a.x * b.x - (a.y * b.y + a.z * b.z + a.w * b.w);
  }
  acc *= 2.0f;
  for (int o = 32; o > 0; o >>= 1) acc += __shfl_down(acc, o, 64);
  __shared__ float lds[4];
  int lane = threadIdx.x & 63;
  int w = threadIdx.x >> 6;
  if (lane == 0) lds[w] = acc;
  __syncthreads();
  if (threadIdx.x == 0) atomicAdd(out, lds[0] + lds[1] + lds[2] + lds[3]);
}

extern "C" void kernel_launch(void* const* d_in, const int* in_sizes, int n_in,
                              void* d_out, int out_size, void* d_ws, size_t ws_size,
                              hipStream_t stream) {
  const float* off  = (const float*)d_in[0];   // [3,49,49,49] f32
  const float* topo = (const float*)d_in[1];   // [110592,96] f32
  float4* ws4 = (float4*)d_ws;                 // 110592 float4 = 1.77 MB
  float* out  = (float*)d_out;                 // scalar f32

  k_cell<<<dim3(NCELLS / CB), dim3(CB * NW), 0, stream>>>(off, topo, ws4, out);
  k_pair<<<dim3(NCELLS / 256), dim3(256), 0, stream>>>(ws4, out);
}

// Round 6
// 91.192 us; speedup vs baseline: 2.5354x; 1.0011x over previous
//
#include <hip/hip_runtime.h>
#include <cstdint>

#define NCELLS (48*48*48)   // 110592
#define NT 48
#define CB 64               // cells per block in k_cell
#define NW 8                // waves per block; each wave does 6 tris
#define PITCH 97            // LDS row pitch (97 % 32 == 1 -> 2 lanes/bank = free)

// ---------------- compile-time exact numpy RNG reproduction ----------------
namespace nprng {
typedef unsigned __int128 u128;
struct PCG { u128 state; u128 inc; int has32; uint32_t cached; };

constexpr u128 mult128() {
  return (((u128)2549297995355413924ULL) << 64) | (u128)4865540595714422341ULL;
}
constexpr void step(PCG& g) { g.state = g.state * mult128() + g.inc; }
constexpr uint64_t out64(const PCG& g) {
  uint64_t x = (uint64_t)(g.state >> 64) ^ (uint64_t)g.state;
  unsigned rot = (unsigned)(g.state >> 122);
  return (x >> rot) | (x << ((64u - rot) & 63u));
}
constexpr uint64_t next64(PCG& g) { step(g); return out64(g); }
constexpr uint32_t next32(PCG& g) {
  if (g.has32) { g.has32 = 0; return g.cached; }
  uint64_t v = next64(g);
  g.has32 = 1; g.cached = (uint32_t)(v >> 32);
  return (uint32_t)v;
}
constexpr uint32_t lemire32(PCG& g, uint32_t rngmax) {
  const uint32_t rng_excl = rngmax + 1u;
  uint64_t m = (uint64_t)next32(g) * (uint64_t)rng_excl;
  uint32_t leftover = (uint32_t)m;
  if (leftover < rng_excl) {
    const uint32_t threshold = (uint32_t)((0xFFFFFFFFu - rngmax) % rng_excl);
    while (leftover < threshold) {
      m = (uint64_t)next32(g) * (uint64_t)rng_excl;
      leftover = (uint32_t)m;
    }
  }
  return (uint32_t)(m >> 32);
}
constexpr uint64_t rbu(PCG& g, uint64_t rngmax) {
  if (rngmax == 0) return 0;
  return (uint64_t)lemire32(g, (uint32_t)rngmax);
}
constexpr uint32_t hashmix(uint32_t v, uint32_t& hc) {
  v ^= hc; hc *= 0x931e8875u; v *= hc; v ^= v >> 16; return v;
}
constexpr uint32_t mix2(uint32_t x, uint32_t y) {
  uint32_t r = 0xca01f9ddu * x - 0x4973f715u * y; r ^= r >> 16; return r;
}
constexpr PCG seed_pcg0() {
  PCG g{0, 0, 0, 0};
  uint32_t pool[4] = {};
  uint32_t hc = 0x43b0d7e5u;
  for (int i = 0; i < 4; i++) pool[i] = hashmix(0u, hc);
  for (int s = 0; s < 4; s++)
    for (int d = 0; d < 4; d++)
      if (s != d) pool[d] = mix2(pool[d], hashmix(pool[s], hc));
  uint32_t st[8] = {};
  uint32_t hb = 0x8b51f9ddu;
  for (int i = 0; i < 8; i++) {
    uint32_t v = pool[i & 3];
    v ^= hb; hb *= 0x58f38dedu; v *= hb; v ^= v >> 16;
    st[i] = v;
  }
  uint64_t w[4] = {};
  for (int i = 0; i < 4; i++) w[i] = (uint64_t)st[2 * i] | ((uint64_t)st[2 * i + 1] << 32);
  u128 initstate = (((u128)w[0]) << 64) | (u128)w[1];
  u128 initseq   = (((u128)w[2]) << 64) | (u128)w[3];
  g.state = 0; g.inc = (initseq << 1) | (u128)1;
  step(g); g.state += initstate; step(g);
  g.has32 = 0; g.cached = 0;
  return g;
}
constexpr void choice_nr(PCG& g, int pop, int n, int* outv, bool shuf) {
  uint64_t hs[64] = {};
  uint64_t set_size = (uint64_t)(1.2 * (double)n);
  uint64_t mask = set_size;
  mask |= mask >> 1; mask |= mask >> 2; mask |= mask >> 4;
  mask |= mask >> 8; mask |= mask >> 16; mask |= mask >> 32;
  for (int i = 0; i < 64; i++) hs[i] = ~0ULL;
  for (int j = pop - n; j < pop; j++) {
    uint64_t val = rbu(g, (uint64_t)j);
    uint64_t loc = val & mask;
    while (hs[loc] != ~0ULL && hs[loc] != val) loc = (loc + 1) & mask;
    if (hs[loc] == ~0ULL) { hs[loc] = val; outv[j - (pop - n)] = (int)val; }
    else {
      loc = (uint64_t)j & mask;
      while (hs[loc] != ~0ULL) loc = (loc + 1) & mask;
      hs[loc] = (uint64_t)j;
      outv[j - (pop - n)] = j;
    }
  }
  if (shuf) {
    for (int i = n - 1; i >= 1; i--) {
      uint64_t j = rbu(g, (uint64_t)i);
      int t = outv[i]; outv[i] = outv[(int)j]; outv[(int)j] = t;
    }
  }
}
} // namespace nprng

struct TriTab3 {
  int   delta[NT][3];
  float ub[NT][3];
  float wb[NT][3];
  int   a0[NT], a1[NT], a2[NT];
  int   tto[NT];
};

constexpr TriTab3 make_tab() {
  TriTab3 T{};
  nprng::PCG g = nprng::seed_pcg0();
  int tri[NT][3] = {};
  for (int t = 0; t < NT; t++) nprng::choice_nr(g, 12, 3, tri[t], true);
  int tt[NT] = {};
  nprng::choice_nr(g, 96, NT, tt, true);
  for (int i = 1; i < NT; i++) {
    int v = tt[i], j = i - 1;
    while (j >= 0 && tt[j] > v) { tt[j + 1] = tt[j]; j--; }
    tt[j + 1] = v;
  }
  constexpr int EC[12][3] = {{0,0,0},{0,1,0},{0,0,1},{0,1,1},
                             {0,0,0},{1,0,0},{0,0,1},{1,0,1},
                             {0,0,0},{1,0,0},{0,1,0},{1,1,0}};
  constexpr int EA[12] = {0,0,0,0,1,1,1,1,2,2,2,2};
  for (int t = 0; t < NT; t++) {
    float B[3][3] = {};
    int ax[3] = {};
    for (int k = 0; k < 3; k++) {
      int e = tri[t][k];
      int a = EA[e];
      ax[k] = a;
      T.delta[t][k] = a * 117649 + EC[e][0] * 2401 + EC[e][1] * 49 + EC[e][2];
      B[k][0] = (float)EC[e][0]; B[k][1] = (float)EC[e][1]; B[k][2] = (float)EC[e][2];
      B[k][a] += 0.5f;
    }
    for (int c = 0; c < 3; c++) {
      T.ub[t][c] = B[1][c] - B[0][c];
      T.wb[t][c] = B[2][c] - B[0][c];
    }
    T.a0[t] = ax[0]; T.a1[t] = ax[1]; T.a2[t] = ax[2];
    T.tto[t] = tt[t];
  }
  return T;
}

static constexpr TriTab3 TAB = make_tab();

// ---------------- kernels ----------------
template <int t>
__device__ __forceinline__ void do1(const float* __restrict__ off, int base,
                                    const float* __restrict__ myrow,
                                    float& s, float& mx, float& my, float& mz) {
  constexpr int D0 = TAB.delta[t][0], D1 = TAB.delta[t][1], D2 = TAB.delta[t][2];
  constexpr int A0 = TAB.a0[t], A1 = TAB.a1[t], A2 = TAB.a2[t];
  float p  = myrow[TAB.tto[t]];
  float d0 = off[base + D0];
  float d1 = off[base + D1];
  float d2 = off[base + D2];
  float ux = TAB.ub[t][0] + (A1 == 0 ? d1 : 0.0f) - (A0 == 0 ? d0 : 0.0f);
  float uy = TAB.ub[t][1] + (A1 == 1 ? d1 : 0.0f) - (A0 == 1 ? d0 : 0.0f);
  float uz = TAB.ub[t][2] + (A1 == 2 ? d1 : 0.0f) - (A0 == 2 ? d0 : 0.0f);
  float wx = TAB.wb[t][0] + (A2 == 0 ? d2 : 0.0f) - (A0 == 0 ? d0 : 0.0f);
  float wy = TAB.wb[t][1] + (A2 == 1 ? d2 : 0.0f) - (A0 == 1 ? d0 : 0.0f);
  float wz = TAB.wb[t][2] + (A2 == 2 ? d2 : 0.0f) - (A0 == 2 ? d0 : 0.0f);
  float cxv = uy * wz - uz * wy;
  float cyv = uz * wx - ux * wz;
  float czv = ux * wy - uy * wx;
  float nn = cxv * cxv + cyv * cyv + czv * czv + 1e-8f;
  float rinv = rsqrtf(nn);
  s += p;
  float f = p * rinv;
  mx += f * cxv;
  my += f * cyv;
  mz += f * czv;
}

template <int T0>
__device__ __forceinline__ void do6(const float* __restrict__ off, int base,
                                    const float* __restrict__ myrow,
                                    float& s, float& mx, float& my, float& mz) {
  do1<T0 + 0>(off, base, myrow, s, mx, my, mz);
  do1<T0 + 1>(off, base, myrow, s, mx, my, mz);
  do1<T0 + 2>(off, base, myrow, s, mx, my, mz);
  do1<T0 + 3>(off, base, myrow, s, mx, my, mz);
  do1<T0 + 4>(off, base, myrow, s, mx, my, mz);
  do1<T0 + 5>(off, base, myrow, s, mx, my, mz);
}

// 64 cells/block, 512 threads (8 waves); wave w -> tris [6w, 6w+6).
// 33 KB LDS -> 4 blocks/CU -> 32 waves/CU (hardware max) to hide
// staging latency + barrier drains. readfirstlane -> scalar dispatch,
// each wave runs exactly one folded-constant body.
__global__ __launch_bounds__(CB * NW) void k_cell(const float* __restrict__ off,
                                                  const float* __restrict__ topo,
                                                  float4* __restrict__ ws4,
                                                  float* __restrict__ out) {
  __shared__ float lds[CB * PITCH];
  __shared__ float4 red[CB * NW];
  const int tid = threadIdx.x;
  const int lane = tid & 63;
  const int cell0 = blockIdx.x * CB;

  if (blockIdx.x == 0 && tid == 0) *out = 0.0f;  // zero accumulator for k_pair

  // ---- coalesced staging: 64 rows x 24 float4 = 1536 float4, linear ----
  const float4* trow = (const float4*)(topo + (size_t)cell0 * 96);
#pragma unroll
  for (int it = 0; it < 3; ++it) {
    int ch = tid + CB * NW * it;
    float4 v = trow[ch];
    int r  = ch / 24;
    int c4 = (ch % 24) * 4;
    float* dst = &lds[r * PITCH + c4];
    dst[0] = v.x; dst[1] = v.y; dst[2] = v.z; dst[3] = v.w;
  }
  __syncthreads();

  // ---- per-(cell, sixth) compute ----
  const int cell = cell0 + lane;
  const int z = cell % 48;
  const int y = (cell / 48) % 48;
  const int x = cell / 2304;
  const int base = (x * 49 + y) * 49 + z;
  const float* myrow = &lds[lane * PITCH];

  float s = 0.f, mx = 0.f, my = 0.f, mz = 0.f;
  const int wvu = __builtin_amdgcn_readfirstlane(tid >> 6);  // SGPR-uniform
  if (wvu == 0)      do6<0>(off, base, myrow, s, mx, my, mz);
  else if (wvu == 1) do6<6>(off, base, myrow, s, mx, my, mz);
  else if (wvu == 2) do6<12>(off, base, myrow, s, mx, my, mz);
  else if (wvu == 3) do6<18>(off, base, myrow, s, mx, my, mz);
  else if (wvu == 4) do6<24>(off, base, myrow, s, mx, my, mz);
  else if (wvu == 5) do6<30>(off, base, myrow, s, mx, my, mz);
  else if (wvu == 6) do6<36>(off, base, myrow, s, mx, my, mz);
  else               do6<42>(off, base, myrow, s, mx, my, mz);

  red[tid] = make_float4(s, mx, my, mz);
  __syncthreads();

  // ---- cross-wave combine: wave 0 sums the 8 eighths, writes float4 ----
  if (tid < 64) {
    float sx = 0.f, sy = 0.f, sz = 0.f, sw = 0.f;
#pragma unroll
    for (int w = 0; w < NW; w++) {
      float4 a = red[lane + 64 * w];
      sx += a.x; sy += a.y; sz += a.z; sw += a.w;
    }
    ws4[cell0 + lane] = make_float4(sx, sy, sz, sw);
  }
}

__global__ __launch_bounds__(256) void k_pair(const float4* __restrict__ ws4,
                                              float* __restrict__ out) {
  int cell = blockIdx.x * 256 + threadIdx.x;
  int z = cell % 48;
  int y = (cell / 48) % 48;
  int x = cell / 2304;
  float4 a = ws4[cell];
  float acc = a.x * a.x - (a.y * a.y + a.z * a.z + a.w * a.w);
  if (z < 47) {
    float4 b = ws4[cell + 1];
    acc += a.x * b.x - (a.y * b.y + a.z * b.z + a.w * b.w);
  }
  if (y < 47) {
    float4 b = ws4[cell + 48];
    acc += a.x * b.x - (a.y * b.y + a.z * b.z + a.w * b.w);
  }
  if (x < 47) {
    float4 b = ws4[cell + 2304];
    acc += a.x * b.x - (a.y * b.y + a.z * b.z + a.w * b.w);
  }
  acc *= 2.0f;
  for (int o = 32; o > 0; o >>= 1) acc += __shfl_down(acc, o, 64);
  __shared__ float lds[4];
  int lane = threadIdx.x & 63;
  int w = threadIdx.x >> 6;
  if (lane == 0) lds[w] = acc;
  __syncthreads();
  if (threadIdx.x == 0) atomicAdd(out, lds[0] + lds[1] + lds[2] + lds[3]);
}

extern "C" void kernel_launch(void* const* d_in, const int* in_sizes, int n_in,
                              void* d_out, int out_size, void* d_ws, size_t ws_size,
                              hipStream_t stream) {
  const float* off  = (const float*)d_in[0];   // [3,49,49,49] f32
  const float* topo = (const float*)d_in[1];   // [110592,96] f32
  float4* ws4 = (float4*)d_ws;                 // 110592 float4 = 1.77 MB
  float* out  = (float*)d_out;                 // scalar f32

  k_cell<<<dim3(NCELLS / CB), dim3(CB * NW), 0, stream>>>(off, topo, ws4, out);
  k_pair<<<dim3(NCELLS / 256), dim3(256), 0, stream>>>(ws4, out);
}

// Round 7
// 90.811 us; speedup vs baseline: 2.5461x; 1.0042x over previous
//
#include <hip/hip_runtime.h>
#include <cstdint>

#define NCELLS (48*48*48)   // 110592
#define NT 48
#define CB 64               // cells per block in k_cell
#define NW 8                // waves per block; each wave does 6 tris
#define PITCH 97            // topo LDS row pitch (97 % 32 == 1 -> 2 lanes/bank = free)
#define OFFE 882            // staged off region: 3a * 2dx * 3dy * 49z floats

// ---------------- compile-time exact numpy RNG reproduction ----------------
namespace nprng {
typedef unsigned __int128 u128;
struct PCG { u128 state; u128 inc; int has32; uint32_t cached; };

constexpr u128 mult128() {
  return (((u128)2549297995355413924ULL) << 64) | (u128)4865540595714422341ULL;
}
constexpr void step(PCG& g) { g.state = g.state * mult128() + g.inc; }
constexpr uint64_t out64(const PCG& g) {
  uint64_t x = (uint64_t)(g.state >> 64) ^ (uint64_t)g.state;
  unsigned rot = (unsigned)(g.state >> 122);
  return (x >> rot) | (x << ((64u - rot) & 63u));
}
constexpr uint64_t next64(PCG& g) { step(g); return out64(g); }
constexpr uint32_t next32(PCG& g) {
  if (g.has32) { g.has32 = 0; return g.cached; }
  uint64_t v = next64(g);
  g.has32 = 1; g.cached = (uint32_t)(v >> 32);
  return (uint32_t)v;
}
constexpr uint32_t lemire32(PCG& g, uint32_t rngmax) {
  const uint32_t rng_excl = rngmax + 1u;
  uint64_t m = (uint64_t)next32(g) * (uint64_t)rng_excl;
  uint32_t leftover = (uint32_t)m;
  if (leftover < rng_excl) {
    const uint32_t threshold = (uint32_t)((0xFFFFFFFFu - rngmax) % rng_excl);
    while (leftover < threshold) {
      m = (uint64_t)next32(g) * (uint64_t)rng_excl;
      leftover = (uint32_t)m;
    }
  }
  return (uint32_t)(m >> 32);
}
constexpr uint64_t rbu(PCG& g, uint64_t rngmax) {
  if (rngmax == 0) return 0;
  return (uint64_t)lemire32(g, (uint32_t)rngmax);
}
constexpr uint32_t hashmix(uint32_t v, uint32_t& hc) {
  v ^= hc; hc *= 0x931e8875u; v *= hc; v ^= v >> 16; return v;
}
constexpr uint32_t mix2(uint32_t x, uint32_t y) {
  uint32_t r = 0xca01f9ddu * x - 0x4973f715u * y; r ^= r >> 16; return r;
}
constexpr PCG seed_pcg0() {
  PCG g{0, 0, 0, 0};
  uint32_t pool[4] = {};
  uint32_t hc = 0x43b0d7e5u;
  for (int i = 0; i < 4; i++) pool[i] = hashmix(0u, hc);
  for (int s = 0; s < 4; s++)
    for (int d = 0; d < 4; d++)
      if (s != d) pool[d] = mix2(pool[d], hashmix(pool[s], hc));
  uint32_t st[8] = {};
  uint32_t hb = 0x8b51f9ddu;
  for (int i = 0; i < 8; i++) {
    uint32_t v = pool[i & 3];
    v ^= hb; hb *= 0x58f38dedu; v *= hb; v ^= v >> 16;
    st[i] = v;
  }
  uint64_t w[4] = {};
  for (int i = 0; i < 4; i++) w[i] = (uint64_t)st[2 * i] | ((uint64_t)st[2 * i + 1] << 32);
  u128 initstate = (((u128)w[0]) << 64) | (u128)w[1];
  u128 initseq   = (((u128)w[2]) << 64) | (u128)w[3];
  g.state = 0; g.inc = (initseq << 1) | (u128)1;
  step(g); g.state += initstate; step(g);
  g.has32 = 0; g.cached = 0;
  return g;
}
constexpr void choice_nr(PCG& g, int pop, int n, int* outv, bool shuf) {
  uint64_t hs[64] = {};
  uint64_t set_size = (uint64_t)(1.2 * (double)n);
  uint64_t mask = set_size;
  mask |= mask >> 1; mask |= mask >> 2; mask |= mask >> 4;
  mask |= mask >> 8; mask |= mask >> 16; mask |= mask >> 32;
  for (int i = 0; i < 64; i++) hs[i] = ~0ULL;
  for (int j = pop - n; j < pop; j++) {
    uint64_t val = rbu(g, (uint64_t)j);
    uint64_t loc = val & mask;
    while (hs[loc] != ~0ULL && hs[loc] != val) loc = (loc + 1) & mask;
    if (hs[loc] == ~0ULL) { hs[loc] = val; outv[j - (pop - n)] = (int)val; }
    else {
      loc = (uint64_t)j & mask;
      while (hs[loc] != ~0ULL) loc = (loc + 1) & mask;
      hs[loc] = (uint64_t)j;
      outv[j - (pop - n)] = j;
    }
  }
  if (shuf) {
    for (int i = n - 1; i >= 1; i--) {
      uint64_t j = rbu(g, (uint64_t)i);
      int t = outv[i]; outv[i] = outv[(int)j]; outv[(int)j] = t;
    }
  }
}
} // namespace nprng

struct TriTab3 {
  float ub[NT][3];
  float wb[NT][3];
  int   a0[NT], a1[NT], a2[NT];
  int   lofc[NT][3];   // LDS off index const: ((a*2+cx)*3+cy)*49 + cz
  int   tto[NT];
};

constexpr TriTab3 make_tab() {
  TriTab3 T{};
  nprng::PCG g = nprng::seed_pcg0();
  int tri[NT][3] = {};
  for (int t = 0; t < NT; t++) nprng::choice_nr(g, 12, 3, tri[t], true);
  int tt[NT] = {};
  nprng::choice_nr(g, 96, NT, tt, true);
  for (int i = 1; i < NT; i++) {
    int v = tt[i], j = i - 1;
    while (j >= 0 && tt[j] > v) { tt[j + 1] = tt[j]; j--; }
    tt[j + 1] = v;
  }
  constexpr int EC[12][3] = {{0,0,0},{0,1,0},{0,0,1},{0,1,1},
                             {0,0,0},{1,0,0},{0,0,1},{1,0,1},
                             {0,0,0},{1,0,0},{0,1,0},{1,1,0}};
  constexpr int EA[12] = {0,0,0,0,1,1,1,1,2,2,2,2};
  for (int t = 0; t < NT; t++) {
    float B[3][3] = {};
    int ax[3] = {};
    for (int k = 0; k < 3; k++) {
      int e = tri[t][k];
      int a = EA[e];
      ax[k] = a;
      T.lofc[t][k] = ((a * 2 + EC[e][0]) * 3 + EC[e][1]) * 49 + EC[e][2];
      B[k][0] = (float)EC[e][0]; B[k][1] = (float)EC[e][1]; B[k][2] = (float)EC[e][2];
      B[k][a] += 0.5f;
    }
    for (int c = 0; c < 3; c++) {
      T.ub[t][c] = B[1][c] - B[0][c];
      T.wb[t][c] = B[2][c] - B[0][c];
    }
    T.a0[t] = ax[0]; T.a1[t] = ax[1]; T.a2[t] = ax[2];
    T.tto[t] = tt[t];
  }
  return T;
}

static constexpr TriTab3 TAB = make_tab();

// ---------------- kernels ----------------
// One triangle; table values are immediates; d0/d1/d2 come from the block's
// staged off-region in LDS (ds_read_b32, compile-time offsets).
template <int t>
__device__ __forceinline__ void do1(const float* __restrict__ loff, int lanebase,
                                    const float* __restrict__ myrow,
                                    float& s, float& mx, float& my, float& mz) {
  constexpr int L0 = TAB.lofc[t][0], L1 = TAB.lofc[t][1], L2 = TAB.lofc[t][2];
  constexpr int A0 = TAB.a0[t], A1 = TAB.a1[t], A2 = TAB.a2[t];
  float p  = myrow[TAB.tto[t]];
  float d0 = loff[lanebase + L0];
  float d1 = loff[lanebase + L1];
  float d2 = loff[lanebase + L2];
  float ux = TAB.ub[t][0] + (A1 == 0 ? d1 : 0.0f) - (A0 == 0 ? d0 : 0.0f);
  float uy = TAB.ub[t][1] + (A1 == 1 ? d1 : 0.0f) - (A0 == 1 ? d0 : 0.0f);
  float uz = TAB.ub[t][2] + (A1 == 2 ? d1 : 0.0f) - (A0 == 2 ? d0 : 0.0f);
  float wx = TAB.wb[t][0] + (A2 == 0 ? d2 : 0.0f) - (A0 == 0 ? d0 : 0.0f);
  float wy = TAB.wb[t][1] + (A2 == 1 ? d2 : 0.0f) - (A0 == 1 ? d0 : 0.0f);
  float wz = TAB.wb[t][2] + (A2 == 2 ? d2 : 0.0f) - (A0 == 2 ? d0 : 0.0f);
  float cxv = uy * wz - uz * wy;
  float cyv = uz * wx - ux * wz;
  float czv = ux * wy - uy * wx;
  float nn = cxv * cxv + cyv * cyv + czv * czv + 1e-8f;
  float rinv = rsqrtf(nn);
  s += p;
  float f = p * rinv;
  mx += f * cxv;
  my += f * cyv;
  mz += f * czv;
}

template <int T0>
__device__ __forceinline__ void do6(const float* __restrict__ loff, int lanebase,
                                    const float* __restrict__ myrow,
                                    float& s, float& mx, float& my, float& mz) {
  do1<T0 + 0>(loff, lanebase, myrow, s, mx, my, mz);
  do1<T0 + 1>(loff, lanebase, myrow, s, mx, my, mz);
  do1<T0 + 2>(loff, lanebase, myrow, s, mx, my, mz);
  do1<T0 + 3>(loff, lanebase, myrow, s, mx, my, mz);
  do1<T0 + 4>(loff, lanebase, myrow, s, mx, my, mz);
  do1<T0 + 5>(loff, lanebase, myrow, s, mx, my, mz);
}

// 64 cells/block, 512 threads (8 waves); wave w -> tris [6w, 6w+6).
// Both topo slab AND the off edge-region are staged in LDS; compute phase
// issues zero per-lane global loads.
__global__ __launch_bounds__(CB * NW) void k_cell(const float* __restrict__ off,
                                                  const float* __restrict__ topo,
                                                  float4* __restrict__ ws4,
                                                  float* __restrict__ out) {
  __shared__ float lds[CB * PITCH];
  __shared__ float loff[OFFE];
  __shared__ float4 red[CB * NW];
  const int tid = threadIdx.x;
  const int lane = tid & 63;
  const int cell0 = blockIdx.x * CB;

  if (blockIdx.x == 0 && tid == 0) *out = 0.0f;  // zero accumulator for k_pair

  // ---- stage off region: x fixed, y0..y0+2, z 0..48 -> 882 floats ----
  const int x0 = cell0 / 2304;
  const int y0 = (cell0 / 48) % 48;
  for (int e = tid; e < OFFE; e += CB * NW) {
    int r = e / 49, zz = e % 49;       // r = (a*2+dx)*3+dy
    int dy = r % 3, rr = r / 3;
    int dx = rr & 1, a = rr >> 1;
    loff[e] = off[a * 117649 + (x0 + dx) * 2401 + (y0 + dy) * 49 + zz];
  }

  // ---- coalesced topo staging: 64 rows x 24 float4 = 1536 float4, linear ----
  const float4* trow = (const float4*)(topo + (size_t)cell0 * 96);
#pragma unroll
  for (int it = 0; it < 3; ++it) {
    int ch = tid + CB * NW * it;
    float4 v = trow[ch];
    int r  = ch / 24;
    int c4 = (ch % 24) * 4;
    float* dst = &lds[r * PITCH + c4];
    dst[0] = v.x; dst[1] = v.y; dst[2] = v.z; dst[3] = v.w;
  }
  __syncthreads();

  // ---- per-(cell, sixth) compute ----
  const int cell = cell0 + lane;
  const int z = cell % 48;
  const int ly = ((cell / 48) % 48) - y0;        // 0 or 1 (no x-cross mid-block)
  const int lanebase = ly * 49 + z;
  const float* myrow = &lds[lane * PITCH];

  float s = 0.f, mx = 0.f, my = 0.f, mz = 0.f;
  const int wvu = __builtin_amdgcn_readfirstlane(tid >> 6);  // SGPR-uniform
  if (wvu == 0)      do6<0>(loff, lanebase, myrow, s, mx, my, mz);
  else if (wvu == 1) do6<6>(loff, lanebase, myrow, s, mx, my, mz);
  else if (wvu == 2) do6<12>(loff, lanebase, myrow, s, mx, my, mz);
  else if (wvu == 3) do6<18>(loff, lanebase, myrow, s, mx, my, mz);
  else if (wvu == 4) do6<24>(loff, lanebase, myrow, s, mx, my, mz);
  else if (wvu == 5) do6<30>(loff, lanebase, myrow, s, mx, my, mz);
  else if (wvu == 6) do6<36>(loff, lanebase, myrow, s, mx, my, mz);
  else               do6<42>(loff, lanebase, myrow, s, mx, my, mz);

  red[tid] = make_float4(s, mx, my, mz);
  __syncthreads();

  // ---- cross-wave combine: wave 0 sums the 8 eighths, writes float4 ----
  if (tid < 64) {
    float sx = 0.f, sy = 0.f, sz = 0.f, sw = 0.f;
#pragma unroll
    for (int w = 0; w < NW; w++) {
      float4 a = red[lane + 64 * w];
      sx += a.x; sy += a.y; sz += a.z; sw += a.w;
    }
    ws4[cell0 + lane] = make_float4(sx, sy, sz, sw);
  }
}

__global__ __launch_bounds__(256) void k_pair(const float4* __restrict__ ws4,
                                              float* __restrict__ out) {
  int cell = blockIdx.x * 256 + threadIdx.x;
  int z = cell % 48;
  int y = (cell / 48) % 48;
  int x = cell / 2304;
  float4 a = ws4[cell];
  float acc = a.x * a.x - (a.y * a.y + a.z * a.z + a.w * a.w);
  if (z < 47) {
    float4 b = ws4[cell + 1];
    acc += a.x * b.x - (a.y * b.y + a.z * b.z + a.w * b.w);
  }
  if (y < 47) {
    float4 b = ws4[cell + 48];
    acc += a.x * b.x - (a.y * b.y + a.z * b.z + a.w * b.w);
  }
  if (x < 47) {
    float4 b = ws4[cell + 2304];
    acc += a.x * b.x - (a.y * b.y + a.z * b.z + a.w * b.w);
  }
  acc *= 2.0f;
  for (int o = 32; o > 0; o >>= 1) acc += __shfl_down(acc, o, 64);
  __shared__ float lds[4];
  int lane = threadIdx.x & 63;
  int w = threadIdx.x >> 6;
  if (lane == 0) lds[w] = acc;
  __syncthreads();
  if (threadIdx.x == 0) atomicAdd(out, lds[0] + lds[1] + lds[2] + lds[3]);
}

extern "C" void kernel_launch(void* const* d_in, const int* in_sizes, int n_in,
                              void* d_out, int out_size, void* d_ws, size_t ws_size,
                              hipStream_t stream) {
  const float* off  = (const float*)d_in[0];   // [3,49,49,49] f32
  const float* topo = (const float*)d_in[1];   // [110592,96] f32
  float4* ws4 = (float4*)d_ws;                 // 110592 float4 = 1.77 MB
  float* out  = (float*)d_out;                 // scalar f32

  k_cell<<<dim3(NCELLS / CB), dim3(CB * NW), 0, stream>>>(off, topo, ws4, out);
  k_pair<<<dim3(NCELLS / 256), dim3(256), 0, stream>>>(ws4, out);
}